// Round 9
// baseline (163.415 us; speedup 1.0000x reference)
//
#include <hip/hip_runtime.h>
#include <hip/hip_bf16.h>

typedef __bf16 bf16x8 __attribute__((ext_vector_type(8)));
typedef float  f32x4  __attribute__((ext_vector_type(4)));

#define N_TOT  8192
#define B_HALF 4096
#define D      256
// exp(sim) = exp2(dot * 10*log2(e)); zn prescaled by sqrt(10*log2(e))
#define SQK1   3.79828254f
#define LN2    0.6931471805599453f

#define RB      128   // rows per block (4 waves x 32)
#define CB      32    // cols per LDS stage
#define SLICE   512   // cols per block
#define NSLICE  16
#define NSTAGE  16    // SLICE/CB
#define LDS_RS  264   // padded row stride (r5-verbatim: measured 0 bank conflicts)

// bare hardware exp2 — ONE v_exp_f32 by construction (exp2f() was the r5-r8
// suspect: OCML accurate path is a guarded multi-instruction sequence)
__device__ __forceinline__ float hexp2(float x) {
    float r;
    asm("v_exp_f32 %0, %1" : "=v"(r) : "v"(x));
    return r;
}

// ---------------- kernel 1: concat + L2-normalize -> bf16 (prescaled) ----------------
__global__ __launch_bounds__(256) void normalize_kernel(
    const float* __restrict__ zi, const float* __restrict__ zj,
    ushort* __restrict__ zn, float* __restrict__ out)
{
    if (blockIdx.x == 0 && threadIdx.x == 0) *out = 0.0f;   // zero accumulator (stream-ordered)
    int row  = (blockIdx.x * 256 + threadIdx.x) >> 6;       // one wave per row
    int lane = threadIdx.x & 63;
    const float* src = (row < B_HALF) ? (zi + (size_t)row * D)
                                      : (zj + (size_t)(row - B_HALF) * D);
    float4 v = ((const float4*)src)[lane];
    float ss = v.x * v.x + v.y * v.y + v.z * v.z + v.w * v.w;
    #pragma unroll
    for (int m = 1; m < 64; m <<= 1) ss += __shfl_xor(ss, m);
    float r = SQK1 / fmaxf(sqrtf(ss), 1e-8f);               // fold exp2-scale into data
    union { ushort4 u4; __hip_bfloat16 h[4]; } o;
    o.h[0] = __float2bfloat16(v.x * r);
    o.h[1] = __float2bfloat16(v.y * r);
    o.h[2] = __float2bfloat16(v.z * r);
    o.h[3] = __float2bfloat16(v.w * r);
    ((ushort4*)zn)[(size_t)row * (D / 4) + lane] = o.u4;
}

// ---------------- kernel 2: fused sim + sum-of-exp ----------------
// grid (64,16): 128 rows x 512 cols per 256-thr block.
// r8 dataflow (32 rows/wave A-hoist = 64 VGPR, PROVEN 88-reg clean alloc) +
// r5 LDS staging (padded LDS_RS=264, PROVEN 0 bank conflicts).
// Deltas vs r8: asm v_exp_f32; no setprio; transposed spartial; 1 staging ptr.
__global__ __launch_bounds__(256) void fused_kernel(
    const ushort* __restrict__ zn,
    float* __restrict__ spartial,   // [NSLICE][N_TOT]  (transposed: coalesced stores)
    float* __restrict__ posdot)     // [N_TOT] prescaled dot
{
    __shared__ ushort lds[2][CB * LDS_RS];   // 2 x 16896 B = 33792

    int tid  = threadIdx.x;
    int lane = tid & 63;
    int w    = tid >> 6;             // 0..3
    int l15  = lane & 15;
    int l4   = lane >> 4;            // 0..3 (k-quarter)
    int r0   = blockIdx.x * RB + w * 32;
    int cs0  = blockIdx.y * SLICE;

    // hoist A: 32 rows x K=256 (2 rowtiles x 8 k-chunks) = 64 VGPRs
    bf16x8 a[2][8];
    #pragma unroll
    for (int rt = 0; rt < 2; ++rt) {
        const ushort* ar = zn + (size_t)(r0 + rt * 16 + l15) * D + l4 * 8;
        #pragma unroll
        for (int kc = 0; kc < 8; ++kc)
            a[rt][kc] = *(const bf16x8*)(ar + kc * 32);
    }

    float srow[2][4];
    #pragma unroll
    for (int rt = 0; rt < 2; ++rt)
        #pragma unroll
        for (int g = 0; g < 4; ++g) srow[rt][g] = 0.f;

    // staging: thread covers chunks tid + i*256; col0 = tid>>5 (0..7 step +8), k16 = tid&31
    const int col0 = tid >> 5, k16 = tid & 31;
    const ushort* gsrc = zn + (size_t)(cs0 + col0) * D + k16 * 8;  // advance 32 cols/stage
    const int lwr = col0 * LDS_RS + k16 * 8;                        // lds write base (ushorts)

    uint4 st[4];
    #pragma unroll
    for (int i = 0; i < 4; ++i) st[i] = *(const uint4*)(gsrc + i * 8 * D);
    gsrc += (size_t)CB * D;
    #pragma unroll
    for (int i = 0; i < 4; ++i) *(uint4*)(&lds[0][lwr + i * 8 * LDS_RS]) = st[i];
    __syncthreads();

    const int lrd = l15 * LDS_RS + l4 * 8;   // B-frag read base for ct=0

    for (int s = 0; s < NSTAGE; ++s) {
        int cur = s & 1;
        if (s + 1 < NSTAGE) {        // prefetch next stage (in flight under MFMA)
            #pragma unroll
            for (int i = 0; i < 4; ++i) st[i] = *(const uint4*)(gsrc + i * 8 * D);
            gsrc += (size_t)CB * D;
        }

        f32x4 acc[2][2] = {};
        #pragma unroll
        for (int kc = 0; kc < 8; ++kc) {
            #pragma unroll
            for (int ct = 0; ct < 2; ++ct) {
                bf16x8 b = *(const bf16x8*)(&lds[cur][lrd + ct * 16 * LDS_RS + kc * 32]);
                acc[0][ct] = __builtin_amdgcn_mfma_f32_16x16x32_bf16(a[0][kc], b, acc[0][ct], 0, 0, 0);
                acc[1][ct] = __builtin_amdgcn_mfma_f32_16x16x32_bf16(a[1][kc], b, acc[1][ct], 0, 0, 0);
            }
        }

        // epilogue: C layout col=l15, row=l4*4+g (m89/m91)
        #pragma unroll
        for (int rt = 0; rt < 2; ++rt) {
            int rowb = r0 + rt * 16;
            #pragma unroll
            for (int ct = 0; ct < 2; ++ct) {
                int colb = cs0 + s * CB + ct * 16;
                bool isdiag = (rowb == colb);
                bool ispos  = ((rowb ^ B_HALF) == colb);
                if (isdiag) {
                    #pragma unroll
                    for (int g = 0; g < 4; ++g) {
                        int rl = l4 * 4 + g;
                        float e = hexp2(acc[rt][ct][g]);
                        srow[rt][g] += (rl != l15) ? e : 0.0f;   // mask self-sim
                    }
                } else if (ispos) {
                    #pragma unroll
                    for (int g = 0; g < 4; ++g) {
                        int rl = l4 * 4 + g;
                        if (rl == l15) posdot[rowb + rl] = acc[rt][ct][g];  // unique writer
                        srow[rt][g] += hexp2(acc[rt][ct][g]);
                    }
                } else {
                    #pragma unroll
                    for (int g = 0; g < 4; ++g)
                        srow[rt][g] += hexp2(acc[rt][ct][g]);
                }
            }
        }

        if (s + 1 < NSTAGE) {
            __syncthreads();         // all waves done reading lds[cur^1] (stage s-1)
            #pragma unroll
            for (int i = 0; i < 4; ++i) *(uint4*)(&lds[cur ^ 1][lwr + i * 8 * LDS_RS]) = st[i];
            __syncthreads();
        }
    }

    // reduce over the 16 column-lanes; store transposed (coalesced-ish)
    #pragma unroll
    for (int rt = 0; rt < 2; ++rt) {
        #pragma unroll
        for (int g = 0; g < 4; ++g) {
            float v = srow[rt][g];
            v += __shfl_xor(v, 1);
            v += __shfl_xor(v, 2);
            v += __shfl_xor(v, 4);
            v += __shfl_xor(v, 8);
            if (l15 == 0) {
                int row = r0 + rt * 16 + l4 * 4 + g;
                spartial[(size_t)blockIdx.y * N_TOT + row] = v;
            }
        }
    }
}

// ---------------- kernel 3: finalize ----------------
__global__ __launch_bounds__(256) void finalize_kernel(
    const float* __restrict__ spartial, const float* __restrict__ posdot,
    float* __restrict__ out)
{
    int i    = blockIdx.x * 256 + threadIdx.x;   // row 0..8191
    int lane = threadIdx.x & 63;
    int wv   = threadIdx.x >> 6;
    float ssum = 0.f;
    #pragma unroll
    for (int k = 0; k < NSLICE; ++k) ssum += spartial[(size_t)k * N_TOT + i];
    float loss = LN2 * (log2f(ssum) - posdot[i]);
    #pragma unroll
    for (int m = 1; m < 64; m <<= 1) loss += __shfl_xor(loss, m);
    __shared__ float red[4];
    if (lane == 0) red[wv] = loss;
    __syncthreads();
    if (threadIdx.x == 0) {
        float t = red[0] + red[1] + red[2] + red[3];
        atomicAdd(out, t * (1.0f / (float)N_TOT));
    }
}

extern "C" void kernel_launch(void* const* d_in, const int* in_sizes, int n_in,
                              void* d_out, int out_size, void* d_ws, size_t ws_size,
                              hipStream_t stream)
{
    const float* zi = (const float*)d_in[0];
    const float* zj = (const float*)d_in[1];
    float* out = (float*)d_out;

    ushort* zn       = (ushort*)d_ws;                                             // 4 MiB
    float*  posdot   = (float*)((char*)d_ws + (size_t)N_TOT * D * 2);             // 32 KiB
    float*  spartial = (float*)((char*)d_ws + (size_t)N_TOT * D * 2 + N_TOT * 4); // 512 KiB

    normalize_kernel<<<N_TOT / 4, 256, 0, stream>>>(zi, zj, zn, out);

    dim3 grid2(N_TOT / RB, NSLICE);
    fused_kernel<<<grid2, 256, 0, stream>>>(zn, spartial, posdot);

    finalize_kernel<<<N_TOT / 256, 256, 0, stream>>>(spartial, posdot, out);
}